// Round 1
// baseline (171.695 us; speedup 1.0000x reference)
//
#include <hip/hip_runtime.h>
#include <math.h>

#define IN_CH 64
#define OUT_CH 64
#define M1 32
#define M2 32
#define HH 512
#define WW 512

// ---------------- workspace layout (floats) ----------------
// F   : [512][64]   cos(2*pi*k*w/512) in cols 0..31, sin(...) in cols 32..63
// Xw  : [64][512][64]  forward w-DFT: re(ky 0..31) | im(ky 0..31)
// XFr : [32][32][64]   [kx][ky][i]
// XFi : [32][32][64]
// Lr  : [64][32][32]   [o][kx][ky]
// Li  : [64][32][32]
// Z   : [64][512][64]  scaled: re | im
static const size_t OFF_F   = 0;
static const size_t OFF_XW  = 32768;
static const size_t OFF_XFR = OFF_XW  + (size_t)64*512*64;
static const size_t OFF_XFI = OFF_XFR + (size_t)32*32*64;
static const size_t OFF_LR  = OFF_XFI + (size_t)32*32*64;
static const size_t OFF_LI  = OFF_LR  + (size_t)64*32*32;
static const size_t OFF_Z   = OFF_LI  + (size_t)64*32*32;

__global__ void build_table(float* __restrict__ F) {
    int idx = blockIdx.x * 256 + threadIdx.x;      // 0..32767
    int w = idx >> 6, j = idx & 63, k = j & 31;
    int m = (k * w) & 511;                          // exact angle reduction
    float ang = (6.283185307179586f / 512.0f) * (float)m;
    float s, c;
    sincosf(ang, &s, &c);
    F[idx] = (j < 32) ? c : s;
}

// Stage A: Xw[row][j] = sgn_j * sum_w x[row][w] * F[w][j]  (sgn: -1 for sin cols)
// GEMM M=32768 (rows = i*512+h), N=64, K=512. BM=64, BN=64, BK=64.
__global__ __launch_bounds__(256) void stageA(const float* __restrict__ x,
                                              const float* __restrict__ F,
                                              float* __restrict__ Xw) {
    __shared__ float xs[64][65];
    __shared__ float fs[64][64];
    int t  = threadIdx.x;
    int tx = t & 15;          // col group (4 cols)
    int ty = t >> 4;          // row group (4 rows)
    int rowBase = blockIdx.x * 64;

    float acc[4][4];
#pragma unroll
    for (int r = 0; r < 4; ++r)
#pragma unroll
        for (int c = 0; c < 4; ++c) acc[r][c] = 0.f;

    for (int w0 = 0; w0 < 512; w0 += 64) {
        // load x tile 64x64 (rows may cross channels; rows are independent)
#pragma unroll
        for (int p = 0; p < 4; ++p) {
            int rl = (t >> 4) + p * 16;
            int c4 = (t & 15) * 4;
            float4 v = *(const float4*)&x[(size_t)(rowBase + rl) * 512 + w0 + c4];
            xs[rl][c4 + 0] = v.x; xs[rl][c4 + 1] = v.y;
            xs[rl][c4 + 2] = v.z; xs[rl][c4 + 3] = v.w;
        }
        // load F tile 64x64 (contiguous)
#pragma unroll
        for (int p = 0; p < 4; ++p) {
            int flat = p * 1024 + t * 4;
            float4 v = *(const float4*)&F[(size_t)w0 * 64 + flat];
            *(float4*)&fs[flat >> 6][flat & 63] = v;
        }
        __syncthreads();
#pragma unroll 8
        for (int w = 0; w < 64; ++w) {
            float4 f4 = *(const float4*)&fs[w][tx * 4];
#pragma unroll
            for (int r = 0; r < 4; ++r) {
                float xv = xs[ty * 4 + r][w];
                acc[r][0] += xv * f4.x; acc[r][1] += xv * f4.y;
                acc[r][2] += xv * f4.z; acc[r][3] += xv * f4.w;
            }
        }
        __syncthreads();
    }
    float sgn = (tx < 8) ? 1.f : -1.f;
#pragma unroll
    for (int r = 0; r < 4; ++r) {
        float4 v = make_float4(acc[r][0] * sgn, acc[r][1] * sgn,
                               acc[r][2] * sgn, acc[r][3] * sgn);
        *(float4*)&Xw[(size_t)(rowBase + ty * 4 + r) * 64 + tx * 4] = v;
    }
}

// Stage B: XF[i,kx,ky] = sum_h Xw[i,h,ky] * e^{-2pi i kx h/512}
// one wave per (i,ky); lane<32 -> Re for kx=lane, lane>=32 -> Im for kx=lane-32
__global__ __launch_bounds__(256) void stageB(const float* __restrict__ Xw,
                                              const float* __restrict__ F,
                                              float* __restrict__ XFr,
                                              float* __restrict__ XFi) {
    int t = threadIdx.x, wid = t >> 6, lane = t & 63;
    int gw = blockIdx.x * 4 + wid;          // 0..2047
    int i = gw >> 5, ky = gw & 31;
    int j = lane & 31;
    bool isIm = lane >= 32;
    const float* xwb = Xw + (size_t)i * 512 * 64 + ky;
    float acc = 0.f;
    for (int h = 0; h < 512; ++h) {
        float xr = xwb[h * 64];
        float xi = xwb[h * 64 + 32];
        float cv = F[h * 64 + j];
        float sv = F[h * 64 + 32 + j];
        // Re: xr*c + xi*s ; Im: xi*c - xr*s
        float a = isIm ? xi : xr;
        float b = isIm ? -xr : xi;
        acc += a * cv + b * sv;
    }
    if (!isIm) XFr[((size_t)j * 32 + ky) * 64 + i] = acc;
    else       XFi[((size_t)j * 32 + ky) * 64 + i] = acc;
}

// Stage C: L[o,kx,ky] = sum_i XF[i,kx,ky] * (Wr+iWi)[i,o,kx,ky]
// grid: (kx 32) x (ochunk 8); 256 threads: ky=t&31, o_local=t>>5
__global__ __launch_bounds__(256) void stageC(const float* __restrict__ XFr,
                                              const float* __restrict__ XFi,
                                              const float* __restrict__ Wr,
                                              const float* __restrict__ Wi,
                                              float* __restrict__ Lr,
                                              float* __restrict__ Li) {
    __shared__ float sxr[32][65];
    __shared__ float sxi[32][65];
    int t = threadIdx.x;
    int kx = blockIdx.x & 31, oc = blockIdx.x >> 5;
    // stage XF slice [ky][i] (2048 floats each)
    for (int q = 0; q < 8; ++q) {
        int idx = t * 8 + q;                 // 0..2047
        sxr[idx >> 6][idx & 63] = XFr[(size_t)kx * 2048 + idx];
        sxi[idx >> 6][idx & 63] = XFi[(size_t)kx * 2048 + idx];
    }
    __syncthreads();
    int ky = t & 31, ol = t >> 5;
    int o = oc * 8 + ol;
    float lr = 0.f, li = 0.f;
    for (int i = 0; i < 64; ++i) {
        float a = sxr[ky][i];
        float b = sxi[ky][i];
        size_t widx = ((size_t)i * 64 + o) * 1024 + kx * 32 + ky;
        float wrv = Wr[widx];
        float wiv = Wi[widx];
        lr += a * wrv - b * wiv;
        li += a * wiv + b * wrv;
    }
    Lr[((size_t)o * 32 + kx) * 32 + ky] = lr;
    Li[((size_t)o * 32 + kx) * 32 + ky] = li;
}

// Stage D: Z[o,h,ky] = c_ky * sum_kx L[o,kx,ky] * e^{+2pi i kx h/512}
// block: (o, hchunk of 64); 4 waves x 16 h each
__global__ __launch_bounds__(256) void stageD(const float* __restrict__ Lr,
                                              const float* __restrict__ Li,
                                              const float* __restrict__ F,
                                              float* __restrict__ Z) {
    __shared__ float sLr[32][32];
    __shared__ float sLi[32][32];
    int t = threadIdx.x;
    int o = blockIdx.x >> 3, hc = blockIdx.x & 7;
    for (int q = 0; q < 4; ++q) {
        int idx = t + q * 256;               // 0..1023
        sLr[idx >> 5][idx & 31] = Lr[(size_t)o * 1024 + idx];
        sLi[idx >> 5][idx & 31] = Li[(size_t)o * 1024 + idx];
    }
    __syncthreads();
    int lane = t & 63, wid = t >> 6;
    int ky = lane & 31;
    bool isIm = lane >= 32;
    float scale = ((ky == 0) ? 1.0f : 2.0f) * (1.0f / (512.0f * 512.0f));
    for (int hh = 0; hh < 16; ++hh) {
        int h = hc * 64 + wid * 16 + hh;
        float re = 0.f, im = 0.f;
#pragma unroll 8
        for (int kx = 0; kx < 32; ++kx) {
            float a = sLr[kx][ky], b = sLi[kx][ky];
            float cv = F[h * 64 + kx];
            float sv = F[h * 64 + 32 + kx];
            re += a * cv - b * sv;
            im += a * sv + b * cv;
        }
        float val = isIm ? im : re;
        Z[((size_t)o * 512 + h) * 64 + lane] = val * scale;
    }
}

// Stage E: out[o,h,w] = sum_{ky<32} Zr[ky]*cos(2pi ky w/512) - Zi[ky]*sin(...)
// block: 512 threads (thread = w), covers (o, 32 h rows)
__global__ __launch_bounds__(512) void stageE(const float* __restrict__ Z,
                                              const float* __restrict__ F,
                                              float* __restrict__ out) {
    __shared__ float zbuf[32][64];
    int t = threadIdx.x;                     // w
    int o = blockIdx.x >> 4, hc = blockIdx.x & 15;
#pragma unroll
    for (int q = 0; q < 4; ++q) {
        int idx = t + q * 512;               // 0..2047
        zbuf[idx >> 6][idx & 63] = Z[((size_t)o * 512 + hc * 32) * 64 + idx];
    }
    __syncthreads();
    float cw[32], sw[32];
#pragma unroll
    for (int k = 0; k < 32; ++k) {
        cw[k] = F[t * 64 + k];
        sw[k] = F[t * 64 + 32 + k];
    }
    for (int r = 0; r < 32; ++r) {
        float a0 = 0.f, a1 = 0.f, a2 = 0.f, a3 = 0.f;
#pragma unroll
        for (int k = 0; k < 32; k += 4) {
            a0 += zbuf[r][k + 0] * cw[k + 0] - zbuf[r][32 + k + 0] * sw[k + 0];
            a1 += zbuf[r][k + 1] * cw[k + 1] - zbuf[r][32 + k + 1] * sw[k + 1];
            a2 += zbuf[r][k + 2] * cw[k + 2] - zbuf[r][32 + k + 2] * sw[k + 2];
            a3 += zbuf[r][k + 3] * cw[k + 3] - zbuf[r][32 + k + 3] * sw[k + 3];
        }
        out[((size_t)o * 512 + hc * 32 + r) * 512 + t] = (a0 + a1) + (a2 + a3);
    }
}

extern "C" void kernel_launch(void* const* d_in, const int* in_sizes, int n_in,
                              void* d_out, int out_size, void* d_ws, size_t ws_size,
                              hipStream_t stream) {
    const float* x  = (const float*)d_in[0];
    const float* Wr = (const float*)d_in[1];
    const float* Wi = (const float*)d_in[2];
    float* out = (float*)d_out;
    float* ws  = (float*)d_ws;

    float* F   = ws + OFF_F;
    float* Xw  = ws + OFF_XW;
    float* XFr = ws + OFF_XFR;
    float* XFi = ws + OFF_XFI;
    float* Lr  = ws + OFF_LR;
    float* Li  = ws + OFF_LI;
    float* Z   = ws + OFF_Z;

    build_table<<<128, 256, 0, stream>>>(F);
    stageA<<<512, 256, 0, stream>>>(x, F, Xw);
    stageB<<<512, 256, 0, stream>>>(Xw, F, XFr, XFi);
    stageC<<<256, 256, 0, stream>>>(XFr, XFi, Wr, Wi, Lr, Li);
    stageD<<<512, 256, 0, stream>>>(Lr, Li, F, Z);
    stageE<<<1024, 512, 0, stream>>>(Z, F, out);
}